// Round 2
// baseline (663.411 us; speedup 1.0000x reference)
//
#include <hip/hip_runtime.h>
#include <math.h>

// TimeWindowBlock round 2.
// R1 post-mortem: LDS-pipe-bound (broadcast ds_read of c = 64x waste, ~190us).
// Fix: precompute c/A per-b into d_ws (kernel A); main kernel reads c via
// wave-uniform (readfirstlane-forced) scalar loads; phase-1 register-blocked
// 4 s/lane x 9 o/wave so LDS k-reads are per-lane-distinct.

#define BB   512
#define WW   8
#define SS   200
#define HH   64
#define FFN  36
#define PADQ 17          // key LDS row stride in float4 (68 floats)

// ---------------- kernel A: c[b][o][h], A[b][o] ----------------
__global__ __launch_bounds__(256)
void precompute_c(const float* __restrict__ query,
                  const float* __restrict__ W1,
                  const float* __restrict__ b1,
                  float* __restrict__ c_ws,
                  float* __restrict__ A_ws)
{
    __shared__ float q_s[HH];
    const int b = blockIdx.x, tid = threadIdx.x;
    if (tid < HH) q_s[tid] = query[b * HH + tid];
    __syncthreads();
    for (int idx = tid; idx < FFN * HH; idx += 256) {
        int o = idx >> 6, h = idx & 63;
        const float* w = W1 + o * 4 * HH;
        c_ws[b * FFN * HH + idx] = w[HH + h] - w[2 * HH + h] + w[3 * HH + h] * q_s[h];
    }
    if (tid < FFN) {
        const float* w = W1 + tid * 4 * HH;
        float a = b1[tid];
        #pragma unroll 8
        for (int h = 0; h < HH; ++h) a += (w[h] + w[2 * HH + h]) * q_s[h];
        A_ws[b * FFN + tid] = a;
    }
}

// ---------------- kernel B: main ----------------
__global__ __launch_bounds__(256, 2)
void twb_main(const float* __restrict__ key,
              const float* __restrict__ c_ws,
              const float* __restrict__ A_ws,
              const float* __restrict__ prelu_a,
              const float* __restrict__ W2,
              const float* __restrict__ b2,
              const int*   __restrict__ mask,
              float*       __restrict__ out)
{
    __shared__ float k_s[SS * PADQ * 4];   // 54,400 B
    __shared__ float part[4 * 256];        // score partials, reused for out partials
    __shared__ float wl[256];
    __shared__ float red[8];

    const int tid = threadIdx.x;
    const int bw  = blockIdx.x;
    const int b   = bw >> 3;

    // ---- stage key tile: coalesced float4 global -> LDS ----
    const float4* gk4 = (const float4*)(key + (size_t)bw * (SS * HH));
    float4* kl4 = (float4*)k_s;
    for (int i = tid; i < (SS * HH) / 4; i += 256) {
        float4 v = gk4[i];
        kl4[(i >> 4) * PADQ + (i & 15)] = v;
    }
    __syncthreads();

    // ---- phase 1: wave owns 9 o's over all s; lane owns 4 s rows ----
    const int lane = tid & 63;
    const int widu = __builtin_amdgcn_readfirstlane(tid >> 6);  // force SGPR
    const float* cg  = c_ws + b * FFN * HH + widu * 9 * HH;     // uniform ptrs
    const float* Ag  = A_ws + b * FFN + widu * 9;
    const float* W2g = W2 + widu * 9;

    float acc[4][9];
    #pragma unroll
    for (int g = 0; g < 4; ++g)
        #pragma unroll
        for (int o = 0; o < 9; ++o) acc[g][o] = 0.0f;

    int srow[4];
    #pragma unroll
    for (int g = 0; g < 4; ++g) {
        int s = lane + 64 * g;
        srow[g] = (s < SS ? s : SS - 1) * PADQ;   // clamp; junk discarded later
    }

    const float4* k4 = (const float4*)k_s;
    #pragma unroll
    for (int ch = 0; ch < 4; ++ch) {
        float4 kr[4][4];
        #pragma unroll
        for (int g = 0; g < 4; ++g)
            #pragma unroll
            for (int j = 0; j < 4; ++j)
                kr[g][j] = k4[srow[g] + ch * 4 + j];
        #pragma unroll
        for (int o = 0; o < 9; ++o) {
            const float4* c4p = (const float4*)(cg + o * HH + ch * 16);
            float4 c0 = c4p[0], c1 = c4p[1], c2 = c4p[2], c3 = c4p[3];
            #pragma unroll
            for (int g = 0; g < 4; ++g) {
                float a = acc[g][o];
                a += kr[g][0].x * c0.x + kr[g][0].y * c0.y + kr[g][0].z * c0.z + kr[g][0].w * c0.w;
                a += kr[g][1].x * c1.x + kr[g][1].y * c1.y + kr[g][1].z * c1.z + kr[g][1].w * c1.w;
                a += kr[g][2].x * c2.x + kr[g][2].y * c2.y + kr[g][2].z * c2.z + kr[g][2].w * c2.w;
                a += kr[g][3].x * c3.x + kr[g][3].y * c3.y + kr[g][3].z * c3.z + kr[g][3].w * c3.w;
                acc[g][o] = a;
            }
        }
    }

    // PReLU + W2 contraction over this wave's 9 o's
    const float pa = prelu_a[0];
    float sc[4] = {0.f, 0.f, 0.f, 0.f};
    #pragma unroll
    for (int o = 0; o < 9; ++o) {
        float Ao = Ag[o], w2o = W2g[o];
        #pragma unroll
        for (int g = 0; g < 4; ++g) {
            float hv = Ao + acc[g][o];
            hv = (hv >= 0.0f) ? hv : pa * hv;
            sc[g] += w2o * hv;
        }
    }
    #pragma unroll
    for (int g = 0; g < 4; ++g) part[widu * 256 + lane + 64 * g] = sc[g];
    __syncthreads();

    // ---- cross-wave score reduction + mask ----
    float msc = -3.0e38f;
    if (tid < SS) {
        float s = part[tid] + part[256 + tid] + part[512 + tid] + part[768 + tid] + b2[0];
        msc = mask[bw * SS + tid] ? -10000.0f : s;
    }
    __syncthreads();   // part reused below

    // ---- softmax over S ----
    float mx = msc;
    #pragma unroll
    for (int off = 32; off > 0; off >>= 1)
        mx = fmaxf(mx, __shfl_xor(mx, off, 64));
    if (lane == 0) red[tid >> 6] = mx;
    __syncthreads();
    const float M = fmaxf(fmaxf(red[0], red[1]), fmaxf(red[2], red[3]));
    float e = (tid < SS) ? __expf(msc - M) : 0.0f;
    float ssum = e;
    #pragma unroll
    for (int off = 32; off > 0; off >>= 1)
        ssum += __shfl_xor(ssum, off, 64);
    if (lane == 0) red[4 + (tid >> 6)] = ssum;
    __syncthreads();
    const float total = red[4] + red[5] + red[6] + red[7];
    if (tid < SS) wl[tid] = e / total;
    __syncthreads();

    // ---- phase 2: out[h] = sum_s k[s][h] * wl[s]; s split over 4 waves ----
    const int wv = tid >> 6, h = tid & 63;
    float p = 0.0f;
    #pragma unroll 5
    for (int s = wv * 50; s < wv * 50 + 50; ++s)
        p += k_s[s * (PADQ * 4) + h] * wl[s];
    part[wv * 64 + h] = p;
    __syncthreads();
    if (tid < 64) {
        float r = part[tid] + part[64 + tid] + part[128 + tid] + part[192 + tid];
        out[(size_t)bw * HH + tid] = r;
    }
}

// ---------------- fallback (round-1 kernel, used if ws too small) ----------------
__global__ __launch_bounds__(256, 2)
void twb_fallback(const float* __restrict__ query,
                  const float* __restrict__ key,
                  const float* __restrict__ W1,
                  const float* __restrict__ b1,
                  const float* __restrict__ prelu_a,
                  const float* __restrict__ W2,
                  const float* __restrict__ b2,
                  const int*   __restrict__ mask,
                  float*       __restrict__ out)
{
    __shared__ float q_s[HH];
    __shared__ float c_s[FFN * HH];
    __shared__ float A_s[FFN];
    __shared__ float W2_s[FFN];
    __shared__ float k_s[SS * PADQ * 4];
    __shared__ float wl[256];
    __shared__ float red[8];
    __shared__ float part[4 * 64];

    const int tid = threadIdx.x;
    const int bw  = blockIdx.x;
    const int b   = bw >> 3;

    if (tid < HH)  q_s[tid]  = query[b * HH + tid];
    if (tid < FFN) W2_s[tid] = W2[tid];
    __syncthreads();

    const float4* gk4 = (const float4*)(key + (size_t)bw * (SS * HH));
    float4* kl4 = (float4*)k_s;
    for (int i = tid; i < (SS * HH) / 4; i += 256) {
        float4 v = gk4[i];
        kl4[(i >> 4) * PADQ + (i & 15)] = v;
    }
    for (int idx = tid; idx < FFN * HH; idx += 256) {
        int o = idx >> 6, h = idx & 63;
        const float* w = W1 + o * (4 * HH);
        c_s[idx] = w[HH + h] - w[2 * HH + h] + w[3 * HH + h] * q_s[h];
    }
    if (tid < FFN) {
        const float* w = W1 + tid * (4 * HH);
        float a = b1[tid];
        for (int h = 0; h < HH; ++h) a += (w[h] + w[2 * HH + h]) * q_s[h];
        A_s[tid] = a;
    }
    __syncthreads();

    const float pa  = prelu_a[0];
    const float bb2 = b2[0];
    float msc = -3.0e38f;
    if (tid < SS) {
        float acc[FFN];
        #pragma unroll
        for (int o = 0; o < FFN; ++o) acc[o] = A_s[o];
        const float4* c4 = (const float4*)c_s;
        const float4* k4 = (const float4*)k_s;
        const int rowbase = tid * PADQ;
        for (int ch = 0; ch < 4; ++ch) {
            float4 kv0 = k4[rowbase + ch * 4 + 0];
            float4 kv1 = k4[rowbase + ch * 4 + 1];
            float4 kv2 = k4[rowbase + ch * 4 + 2];
            float4 kv3 = k4[rowbase + ch * 4 + 3];
            #pragma unroll
            for (int o = 0; o < FFN; ++o) {
                float4 c0 = c4[o * 16 + ch * 4 + 0];
                float4 c1 = c4[o * 16 + ch * 4 + 1];
                float4 c2 = c4[o * 16 + ch * 4 + 2];
                float4 c3 = c4[o * 16 + ch * 4 + 3];
                float a = acc[o];
                a += c0.x * kv0.x + c0.y * kv0.y + c0.z * kv0.z + c0.w * kv0.w;
                a += c1.x * kv1.x + c1.y * kv1.y + c1.z * kv1.z + c1.w * kv1.w;
                a += c2.x * kv2.x + c2.y * kv2.y + c2.z * kv2.z + c2.w * kv2.w;
                a += c3.x * kv3.x + c3.y * kv3.y + c3.z * kv3.z + c3.w * kv3.w;
                acc[o] = a;
            }
        }
        float sc = bb2;
        #pragma unroll
        for (int o = 0; o < FFN; ++o) {
            float a = acc[o];
            a = (a >= 0.0f) ? a : pa * a;
            sc += W2_s[o] * a;
        }
        msc = mask[bw * SS + tid] ? -10000.0f : sc;
    }

    float mx = msc;
    #pragma unroll
    for (int off = 32; off > 0; off >>= 1)
        mx = fmaxf(mx, __shfl_xor(mx, off, 64));
    const int wid = tid >> 6;
    if ((tid & 63) == 0) red[wid] = mx;
    __syncthreads();
    const float M = fmaxf(fmaxf(red[0], red[1]), fmaxf(red[2], red[3]));
    float e = (tid < SS) ? __expf(msc - M) : 0.0f;
    float ssum = e;
    #pragma unroll
    for (int off = 32; off > 0; off >>= 1)
        ssum += __shfl_xor(ssum, off, 64);
    if ((tid & 63) == 0) red[4 + wid] = ssum;
    __syncthreads();
    const float total = red[4] + red[5] + red[6] + red[7];
    if (tid < SS) wl[tid] = e / total;
    __syncthreads();

    const int wv = tid >> 6, h = tid & 63;
    float p = 0.0f;
    for (int s = wv * 50; s < wv * 50 + 50; ++s)
        p += k_s[s * (PADQ * 4) + h] * wl[s];
    part[wv * 64 + h] = p;
    __syncthreads();
    if (tid < 64) {
        float r = part[tid] + part[64 + tid] + part[128 + tid] + part[192 + tid];
        out[(size_t)bw * HH + tid] = r;
    }
}

extern "C" void kernel_launch(void* const* d_in, const int* in_sizes, int n_in,
                              void* d_out, int out_size, void* d_ws, size_t ws_size,
                              hipStream_t stream) {
    const float* query   = (const float*)d_in[0];
    const float* key     = (const float*)d_in[1];
    const float* W1      = (const float*)d_in[2];
    const float* b1      = (const float*)d_in[3];
    const float* prelu_a = (const float*)d_in[4];
    const float* W2      = (const float*)d_in[5];
    const float* b2      = (const float*)d_in[6];
    const int*   mask    = (const int*)d_in[7];
    float* out = (float*)d_out;

    const size_t need = (size_t)(BB * FFN * HH + BB * FFN) * sizeof(float);
    if (ws_size >= need) {
        float* c_ws = (float*)d_ws;
        float* A_ws = c_ws + BB * FFN * HH;
        precompute_c<<<BB, 256, 0, stream>>>(query, W1, b1, c_ws, A_ws);
        twb_main<<<BB * WW, 256, 0, stream>>>(key, c_ws, A_ws, prelu_a,
                                              W2, b2, mask, out);
    } else {
        twb_fallback<<<BB * WW, 256, 0, stream>>>(query, key, W1, b1, prelu_a,
                                                  W2, b2, mask, out);
    }
}

// Round 3
// 537.166 us; speedup vs baseline: 1.2350x; 1.2350x over previous
//
#include <hip/hip_runtime.h>
#include <math.h>

// TimeWindowBlock round 3.
// R2 post-mortem: register blocking spilled (WRITE_SIZE 668MB = scratch).
// R3 = R1 structure (lane = s, acc[36], no spill @88 VGPR) + c/A from global
// workspace via block-uniform addresses -> s_load + v_fmac(v,s,v), killing
// R1's broadcast-LDS bottleneck without R2's register blow-up.

#define BB   512
#define WW   8
#define SS   200
#define HH   64
#define FFN  36
#define PADQ 17          // key LDS row stride in float4 (68 floats)

// ---------------- kernel A: c[b][o][h], A[b][o] ----------------
__global__ __launch_bounds__(256)
void precompute_c(const float* __restrict__ query,
                  const float* __restrict__ W1,
                  const float* __restrict__ b1,
                  float* __restrict__ c_ws,
                  float* __restrict__ A_ws)
{
    __shared__ float q_s[HH];
    const int b = blockIdx.x, tid = threadIdx.x;
    if (tid < HH) q_s[tid] = query[b * HH + tid];
    __syncthreads();
    for (int idx = tid; idx < FFN * HH; idx += 256) {
        int o = idx >> 6, h = idx & 63;
        const float* w = W1 + o * 4 * HH;
        c_ws[b * FFN * HH + idx] = w[HH + h] - w[2 * HH + h] + w[3 * HH + h] * q_s[h];
    }
    if (tid < FFN) {
        const float* w = W1 + tid * 4 * HH;
        float a = b1[tid];
        #pragma unroll 8
        for (int h = 0; h < HH; ++h) a += (w[h] + w[2 * HH + h]) * q_s[h];
        A_ws[b * FFN + tid] = a;
    }
}

// ---------------- kernel B: main ----------------
__global__ __launch_bounds__(256, 2)
void twb_main(const float* __restrict__ key,
              const float* __restrict__ c_ws,
              const float* __restrict__ A_ws,
              const float* __restrict__ prelu_a,
              const float* __restrict__ W2,
              const float* __restrict__ b2,
              const int*   __restrict__ mask,
              float*       __restrict__ out)
{
    __shared__ float k_s[SS * PADQ * 4];   // 54,400 B
    __shared__ float wl[256];              // softmax weights
    __shared__ float red[8];
    __shared__ float part[4 * 64];         // phase-2 partials

    const int tid = threadIdx.x;
    const int bw  = blockIdx.x;
    const int b   = bw >> 3;               // uniform (SGPR)

    // ---- stage key tile: coalesced float4 global -> LDS (padded rows) ----
    const float4* gk4 = (const float4*)(key + (size_t)bw * (SS * HH));
    float4* kl4 = (float4*)k_s;
    for (int i = tid; i < (SS * HH) / 4; i += 256) {
        float4 v = gk4[i];
        kl4[(i >> 4) * PADQ + (i & 15)] = v;
    }
    __syncthreads();

    // ---- phase 1: lane = s (clamped); c/A/W2 via uniform scalar loads ----
    const float* cg  = c_ws + b * FFN * HH;   // block-uniform base
    const float* Ag  = A_ws + b * FFN;
    const int s_cl   = (tid < SS) ? tid : SS - 1;
    const int rowb   = s_cl * PADQ;

    float acc[FFN];
    #pragma unroll
    for (int o = 0; o < FFN; ++o) acc[o] = 0.0f;

    const float4* k4 = (const float4*)k_s;
    #pragma unroll
    for (int ch = 0; ch < 4; ++ch) {
        float4 kv0 = k4[rowb + ch * 4 + 0];
        float4 kv1 = k4[rowb + ch * 4 + 1];
        float4 kv2 = k4[rowb + ch * 4 + 2];
        float4 kv3 = k4[rowb + ch * 4 + 3];
        #pragma unroll
        for (int o = 0; o < FFN; ++o) {
            const float* cp = cg + o * HH + ch * 16;   // uniform -> s_load
            float a = acc[o];
            a += cp[ 0] * kv0.x + cp[ 1] * kv0.y + cp[ 2] * kv0.z + cp[ 3] * kv0.w;
            a += cp[ 4] * kv1.x + cp[ 5] * kv1.y + cp[ 6] * kv1.z + cp[ 7] * kv1.w;
            a += cp[ 8] * kv2.x + cp[ 9] * kv2.y + cp[10] * kv2.z + cp[11] * kv2.w;
            a += cp[12] * kv3.x + cp[13] * kv3.y + cp[14] * kv3.z + cp[15] * kv3.w;
            acc[o] = a;
        }
    }

    // PReLU + W2 contraction (all scalar operands uniform)
    const float pa  = prelu_a[0];
    float sc = b2[0];
    #pragma unroll
    for (int o = 0; o < FFN; ++o) {
        float hv = Ag[o] + acc[o];
        hv = (hv >= 0.0f) ? hv : pa * hv;
        sc += W2[o] * hv;
    }
    float msc = -3.0e38f;
    if (tid < SS)
        msc = mask[bw * SS + tid] ? -10000.0f : sc;

    // ---- softmax over S (shuffle within wave, LDS across waves) ----
    const int lane = tid & 63, wid = tid >> 6;
    float mx = msc;
    #pragma unroll
    for (int off = 32; off > 0; off >>= 1)
        mx = fmaxf(mx, __shfl_xor(mx, off, 64));
    if (lane == 0) red[wid] = mx;
    __syncthreads();
    const float M = fmaxf(fmaxf(red[0], red[1]), fmaxf(red[2], red[3]));
    float e = (tid < SS) ? __expf(msc - M) : 0.0f;
    float ssum = e;
    #pragma unroll
    for (int off = 32; off > 0; off >>= 1)
        ssum += __shfl_xor(ssum, off, 64);
    if (lane == 0) red[4 + wid] = ssum;
    __syncthreads();
    const float total = red[4] + red[5] + red[6] + red[7];
    if (tid < SS) wl[tid] = e / total;
    __syncthreads();

    // ---- phase 2: out[h] = sum_s k[s][h] * wl[s]; s split over 4 waves ----
    const int h = lane;
    float p = 0.0f;
    #pragma unroll 5
    for (int s = wid * 50; s < wid * 50 + 50; ++s)
        p += k_s[s * (PADQ * 4) + h] * wl[s];
    part[wid * 64 + h] = p;
    __syncthreads();
    if (tid < 64) {
        float r = part[tid] + part[64 + tid] + part[128 + tid] + part[192 + tid];
        out[(size_t)bw * HH + tid] = r;
    }
}

// ---------------- fallback (round-1 kernel, used if ws too small) ----------------
__global__ __launch_bounds__(256, 2)
void twb_fallback(const float* __restrict__ query,
                  const float* __restrict__ key,
                  const float* __restrict__ W1,
                  const float* __restrict__ b1,
                  const float* __restrict__ prelu_a,
                  const float* __restrict__ W2,
                  const float* __restrict__ b2,
                  const int*   __restrict__ mask,
                  float*       __restrict__ out)
{
    __shared__ float q_s[HH];
    __shared__ float c_s[FFN * HH];
    __shared__ float A_s[FFN];
    __shared__ float W2_s[FFN];
    __shared__ float k_s[SS * PADQ * 4];
    __shared__ float wl[256];
    __shared__ float red[8];
    __shared__ float part[4 * 64];

    const int tid = threadIdx.x;
    const int bw  = blockIdx.x;
    const int b   = bw >> 3;

    if (tid < HH)  q_s[tid]  = query[b * HH + tid];
    if (tid < FFN) W2_s[tid] = W2[tid];
    __syncthreads();

    const float4* gk4 = (const float4*)(key + (size_t)bw * (SS * HH));
    float4* kl4 = (float4*)k_s;
    for (int i = tid; i < (SS * HH) / 4; i += 256) {
        float4 v = gk4[i];
        kl4[(i >> 4) * PADQ + (i & 15)] = v;
    }
    for (int idx = tid; idx < FFN * HH; idx += 256) {
        int o = idx >> 6, h = idx & 63;
        const float* w = W1 + o * (4 * HH);
        c_s[idx] = w[HH + h] - w[2 * HH + h] + w[3 * HH + h] * q_s[h];
    }
    if (tid < FFN) {
        const float* w = W1 + tid * (4 * HH);
        float a = b1[tid];
        for (int h = 0; h < HH; ++h) a += (w[h] + w[2 * HH + h]) * q_s[h];
        A_s[tid] = a;
    }
    __syncthreads();

    const float pa  = prelu_a[0];
    const float bb2 = b2[0];
    float msc = -3.0e38f;
    if (tid < SS) {
        float acc[FFN];
        #pragma unroll
        for (int o = 0; o < FFN; ++o) acc[o] = A_s[o];
        const float4* c4 = (const float4*)c_s;
        const float4* k4 = (const float4*)k_s;
        const int rowbase = tid * PADQ;
        for (int ch = 0; ch < 4; ++ch) {
            float4 kv0 = k4[rowbase + ch * 4 + 0];
            float4 kv1 = k4[rowbase + ch * 4 + 1];
            float4 kv2 = k4[rowbase + ch * 4 + 2];
            float4 kv3 = k4[rowbase + ch * 4 + 3];
            #pragma unroll
            for (int o = 0; o < FFN; ++o) {
                float4 c0 = c4[o * 16 + ch * 4 + 0];
                float4 c1 = c4[o * 16 + ch * 4 + 1];
                float4 c2 = c4[o * 16 + ch * 4 + 2];
                float4 c3 = c4[o * 16 + ch * 4 + 3];
                float a = acc[o];
                a += c0.x * kv0.x + c0.y * kv0.y + c0.z * kv0.z + c0.w * kv0.w;
                a += c1.x * kv1.x + c1.y * kv1.y + c1.z * kv1.z + c1.w * kv1.w;
                a += c2.x * kv2.x + c2.y * kv2.y + c2.z * kv2.z + c2.w * kv2.w;
                a += c3.x * kv3.x + c3.y * kv3.y + c3.z * kv3.z + c3.w * kv3.w;
                acc[o] = a;
            }
        }
        float sc = bb2;
        #pragma unroll
        for (int o = 0; o < FFN; ++o) {
            float a = acc[o];
            a = (a >= 0.0f) ? a : pa * a;
            sc += W2_s[o] * a;
        }
        msc = mask[bw * SS + tid] ? -10000.0f : sc;
    }

    float mx = msc;
    #pragma unroll
    for (int off = 32; off > 0; off >>= 1)
        mx = fmaxf(mx, __shfl_xor(mx, off, 64));
    const int wid = tid >> 6;
    if ((tid & 63) == 0) red[wid] = mx;
    __syncthreads();
    const float M = fmaxf(fmaxf(red[0], red[1]), fmaxf(red[2], red[3]));
    float e = (tid < SS) ? __expf(msc - M) : 0.0f;
    float ssum = e;
    #pragma unroll
    for (int off = 32; off > 0; off >>= 1)
        ssum += __shfl_xor(ssum, off, 64);
    if ((tid & 63) == 0) red[4 + wid] = ssum;
    __syncthreads();
    const float total = red[4] + red[5] + red[6] + red[7];
    if (tid < SS) wl[tid] = e / total;
    __syncthreads();

    const int wv = tid >> 6, h = tid & 63;
    float p = 0.0f;
    for (int s = wv * 50; s < wv * 50 + 50; ++s)
        p += k_s[s * (PADQ * 4) + h] * wl[s];
    part[wv * 64 + h] = p;
    __syncthreads();
    if (tid < 64) {
        float r = part[tid] + part[64 + tid] + part[128 + tid] + part[192 + tid];
        out[(size_t)bw * HH + tid] = r;
    }
}

extern "C" void kernel_launch(void* const* d_in, const int* in_sizes, int n_in,
                              void* d_out, int out_size, void* d_ws, size_t ws_size,
                              hipStream_t stream) {
    const float* query   = (const float*)d_in[0];
    const float* key     = (const float*)d_in[1];
    const float* W1      = (const float*)d_in[2];
    const float* b1      = (const float*)d_in[3];
    const float* prelu_a = (const float*)d_in[4];
    const float* W2      = (const float*)d_in[5];
    const float* b2      = (const float*)d_in[6];
    const int*   mask    = (const int*)d_in[7];
    float* out = (float*)d_out;

    const size_t need = (size_t)(BB * FFN * HH + BB * FFN) * sizeof(float);
    if (ws_size >= need) {
        float* c_ws = (float*)d_ws;
        float* A_ws = c_ws + BB * FFN * HH;
        precompute_c<<<BB, 256, 0, stream>>>(query, W1, b1, c_ws, A_ws);
        twb_main<<<BB * WW, 256, 0, stream>>>(key, c_ws, A_ws, prelu_a,
                                              W2, b2, mask, out);
    } else {
        twb_fallback<<<BB * WW, 256, 0, stream>>>(query, key, W1, b1, prelu_a,
                                                  W2, b2, mask, out);
    }
}

// Round 4
// 501.873 us; speedup vs baseline: 1.3219x; 1.0703x over previous
//
#include <hip/hip_runtime.h>
#include <math.h>

// TimeWindowBlock round 4.
// R3 post-mortem: compiler would NOT scalarize uniform c-loads (c_ws not
// provably invariant) -> per-lane global_load_dword, L2-latency-bound,
// VALUBusy 16%. R4: force c onto the idle SMEM pipe with inline-asm
// s_load_dwordx16 into SGPRs; FMAs become v_fmac(v,s,v). Lane keeps its
// whole 64-float k row in VGPRs (no acc[36] array, 4 rotating partials).

#define BB   512
#define WW   8
#define SS   200
#define HH   64
#define FFN  36
#define PADQ 17          // key LDS row stride in float4 (68 floats)

typedef float f32x16 __attribute__((ext_vector_type(16)));

struct H1 { f32x16 c0, c1; float A, w2; };
__device__ __forceinline__ H1 sload_h1(const float* pc, const float* pA,
                                       const float* pW) {
    H1 r;
    asm volatile(
        "s_load_dwordx16 %0, %4, 0x0\n\t"
        "s_load_dwordx16 %1, %4, 0x40\n\t"
        "s_load_dword    %2, %5, 0x0\n\t"
        "s_load_dword    %3, %6, 0x0\n\t"
        "s_waitcnt lgkmcnt(0)"
        : "=&s"(r.c0), "=&s"(r.c1), "=&s"(r.A), "=&s"(r.w2)
        : "s"(pc), "s"(pA), "s"(pW));
    return r;
}
struct H2 { f32x16 c2, c3; };
__device__ __forceinline__ H2 sload_h2(const float* pc) {
    H2 r;
    asm volatile(
        "s_load_dwordx16 %0, %2, 0x80\n\t"
        "s_load_dwordx16 %1, %2, 0xc0\n\t"
        "s_waitcnt lgkmcnt(0)"
        : "=&s"(r.c2), "=&s"(r.c3)
        : "s"(pc));
    return r;
}

// ---------------- kernel A: c[b][o][h], A[b][o] ----------------
__global__ __launch_bounds__(256)
void precompute_c(const float* __restrict__ query,
                  const float* __restrict__ W1,
                  const float* __restrict__ b1,
                  float* __restrict__ c_ws,
                  float* __restrict__ A_ws)
{
    __shared__ float q_s[HH];
    const int b = blockIdx.x, tid = threadIdx.x;
    if (tid < HH) q_s[tid] = query[b * HH + tid];
    __syncthreads();
    for (int idx = tid; idx < FFN * HH; idx += 256) {
        int o = idx >> 6, h = idx & 63;
        const float* w = W1 + o * 4 * HH;
        c_ws[b * FFN * HH + idx] = w[HH + h] - w[2 * HH + h] + w[3 * HH + h] * q_s[h];
    }
    if (tid < FFN) {
        const float* w = W1 + tid * 4 * HH;
        float a = b1[tid];
        #pragma unroll 8
        for (int h = 0; h < HH; ++h) a += (w[h] + w[2 * HH + h]) * q_s[h];
        A_ws[b * FFN + tid] = a;
    }
}

// ---------------- kernel B: main ----------------
__global__ __launch_bounds__(256, 2)
void twb_main(const float* __restrict__ key,
              const float* __restrict__ c_ws,
              const float* __restrict__ A_ws,
              const float* __restrict__ prelu_a,
              const float* __restrict__ W2,
              const float* __restrict__ b2,
              const int*   __restrict__ mask,
              float*       __restrict__ out)
{
    __shared__ float k_s[SS * PADQ * 4];   // 54,400 B
    __shared__ float wl[256];
    __shared__ float red[8];
    __shared__ float part[4 * 64];

    const int tid = threadIdx.x;
    const int bw  = blockIdx.x;
    const int b   = bw >> 3;               // uniform (SGPR)

    // ---- stage key tile: coalesced float4 global -> LDS (padded rows) ----
    const float4* gk4 = (const float4*)(key + (size_t)bw * (SS * HH));
    float4* kl4 = (float4*)k_s;
    for (int i = tid; i < (SS * HH) / 4; i += 256) {
        float4 v = gk4[i];
        kl4[(i >> 4) * PADQ + (i & 15)] = v;
    }
    __syncthreads();

    // ---- phase 1: lane = s (clamped); whole k row -> 64 VGPRs ----
    const int s_cl = (tid < SS) ? tid : SS - 1;
    const int rowb = s_cl * PADQ;
    float kvf[64];
    const float4* k4 = (const float4*)k_s;
    #pragma unroll
    for (int j = 0; j < 16; ++j) {
        float4 t = k4[rowb + j];
        kvf[4 * j + 0] = t.x; kvf[4 * j + 1] = t.y;
        kvf[4 * j + 2] = t.z; kvf[4 * j + 3] = t.w;
    }

    const float* cg = c_ws + b * FFN * HH;   // block-uniform bases
    const float* Ab = A_ws + b * FFN;
    const float  pa = prelu_a[0];

    float sc = b2[0];
    for (int o = 0; o < FFN; ++o) {          // rolled: SMEM streamed via asm
        const float* pc = cg + o * HH;
        H1 h1 = sload_h1(pc, Ab + o, W2 + o);
        float d0 = 0.f, d1 = 0.f, d2 = 0.f, d3 = 0.f;
        #pragma unroll
        for (int j = 0; j < 16; ++j) {
            float t0 = h1.c0[j] * kvf[j];
            float t1 = h1.c1[j] * kvf[16 + j];
            if ((j & 3) == 0)      { d0 += t0; d1 += t1; }
            else if ((j & 3) == 1) { d2 += t0; d3 += t1; }
            else if ((j & 3) == 2) { d0 += t0; d1 += t1; }
            else                   { d2 += t0; d3 += t1; }
        }
        H2 h2 = sload_h2(pc);
        #pragma unroll
        for (int j = 0; j < 16; ++j) {
            float t0 = h2.c2[j] * kvf[32 + j];
            float t1 = h2.c3[j] * kvf[48 + j];
            if ((j & 3) == 0)      { d0 += t0; d1 += t1; }
            else if ((j & 3) == 1) { d2 += t0; d3 += t1; }
            else if ((j & 3) == 2) { d0 += t0; d1 += t1; }
            else                   { d2 += t0; d3 += t1; }
        }
        float hv = ((d0 + d1) + (d2 + d3)) + h1.A;
        hv = (hv >= 0.0f) ? hv : pa * hv;
        sc += h1.w2 * hv;
    }

    float msc = -3.0e38f;
    if (tid < SS)
        msc = mask[bw * SS + tid] ? -10000.0f : sc;

    // ---- softmax over S ----
    const int lane = tid & 63, wid = tid >> 6;
    float mx = msc;
    #pragma unroll
    for (int off = 32; off > 0; off >>= 1)
        mx = fmaxf(mx, __shfl_xor(mx, off, 64));
    if (lane == 0) red[wid] = mx;
    __syncthreads();
    const float M = fmaxf(fmaxf(red[0], red[1]), fmaxf(red[2], red[3]));
    float e = (tid < SS) ? __expf(msc - M) : 0.0f;
    float ssum = e;
    #pragma unroll
    for (int off = 32; off > 0; off >>= 1)
        ssum += __shfl_xor(ssum, off, 64);
    if (lane == 0) red[4 + wid] = ssum;
    __syncthreads();
    const float total = red[4] + red[5] + red[6] + red[7];
    if (tid < SS) wl[tid] = e / total;
    __syncthreads();

    // ---- phase 2: out[h] = sum_s k[s][h] * wl[s]; s split over 4 waves ----
    float p = 0.0f;
    #pragma unroll 5
    for (int s = wid * 50; s < wid * 50 + 50; ++s)
        p += k_s[s * (PADQ * 4) + lane] * wl[s];
    part[wid * 64 + lane] = p;
    __syncthreads();
    if (tid < 64) {
        float r = part[tid] + part[64 + tid] + part[128 + tid] + part[192 + tid];
        out[(size_t)bw * HH + tid] = r;
    }
}

// ---------------- fallback (round-1 kernel, used if ws too small) ----------------
__global__ __launch_bounds__(256, 2)
void twb_fallback(const float* __restrict__ query,
                  const float* __restrict__ key,
                  const float* __restrict__ W1,
                  const float* __restrict__ b1,
                  const float* __restrict__ prelu_a,
                  const float* __restrict__ W2,
                  const float* __restrict__ b2,
                  const int*   __restrict__ mask,
                  float*       __restrict__ out)
{
    __shared__ float q_s[HH];
    __shared__ float c_s[FFN * HH];
    __shared__ float A_s[FFN];
    __shared__ float W2_s[FFN];
    __shared__ float k_s[SS * PADQ * 4];
    __shared__ float wl[256];
    __shared__ float red[8];
    __shared__ float part[4 * 64];

    const int tid = threadIdx.x;
    const int bw  = blockIdx.x;
    const int b   = bw >> 3;

    if (tid < HH)  q_s[tid]  = query[b * HH + tid];
    if (tid < FFN) W2_s[tid] = W2[tid];
    __syncthreads();

    const float4* gk4 = (const float4*)(key + (size_t)bw * (SS * HH));
    float4* kl4 = (float4*)k_s;
    for (int i = tid; i < (SS * HH) / 4; i += 256) {
        float4 v = gk4[i];
        kl4[(i >> 4) * PADQ + (i & 15)] = v;
    }
    for (int idx = tid; idx < FFN * HH; idx += 256) {
        int o = idx >> 6, h = idx & 63;
        const float* w = W1 + o * (4 * HH);
        c_s[idx] = w[HH + h] - w[2 * HH + h] + w[3 * HH + h] * q_s[h];
    }
    if (tid < FFN) {
        const float* w = W1 + tid * (4 * HH);
        float a = b1[tid];
        for (int h = 0; h < HH; ++h) a += (w[h] + w[2 * HH + h]) * q_s[h];
        A_s[tid] = a;
    }
    __syncthreads();

    const float pa  = prelu_a[0];
    const float bb2 = b2[0];
    float msc = -3.0e38f;
    if (tid < SS) {
        float acc[FFN];
        #pragma unroll
        for (int o = 0; o < FFN; ++o) acc[o] = A_s[o];
        const float4* c4 = (const float4*)c_s;
        const float4* k4 = (const float4*)k_s;
        const int rowbase = tid * PADQ;
        for (int ch = 0; ch < 4; ++ch) {
            float4 kv0 = k4[rowbase + ch * 4 + 0];
            float4 kv1 = k4[rowbase + ch * 4 + 1];
            float4 kv2 = k4[rowbase + ch * 4 + 2];
            float4 kv3 = k4[rowbase + ch * 4 + 3];
            #pragma unroll
            for (int o = 0; o < FFN; ++o) {
                float4 c0 = c4[o * 16 + ch * 4 + 0];
                float4 c1 = c4[o * 16 + ch * 4 + 1];
                float4 c2 = c4[o * 16 + ch * 4 + 2];
                float4 c3 = c4[o * 16 + ch * 4 + 3];
                float a = acc[o];
                a += c0.x * kv0.x + c0.y * kv0.y + c0.z * kv0.z + c0.w * kv0.w;
                a += c1.x * kv1.x + c1.y * kv1.y + c1.z * kv1.z + c1.w * kv1.w;
                a += c2.x * kv2.x + c2.y * kv2.y + c2.z * kv2.z + c2.w * kv2.w;
                a += c3.x * kv3.x + c3.y * kv3.y + c3.z * kv3.z + c3.w * kv3.w;
                acc[o] = a;
            }
        }
        float sc = bb2;
        #pragma unroll
        for (int o = 0; o < FFN; ++o) {
            float a = acc[o];
            a = (a >= 0.0f) ? a : pa * a;
            sc += W2_s[o] * a;
        }
        msc = mask[bw * SS + tid] ? -10000.0f : sc;
    }

    float mx = msc;
    #pragma unroll
    for (int off = 32; off > 0; off >>= 1)
        mx = fmaxf(mx, __shfl_xor(mx, off, 64));
    const int wid = tid >> 6;
    if ((tid & 63) == 0) red[wid] = mx;
    __syncthreads();
    const float M = fmaxf(fmaxf(red[0], red[1]), fmaxf(red[2], red[3]));
    float e = (tid < SS) ? __expf(msc - M) : 0.0f;
    float ssum = e;
    #pragma unroll
    for (int off = 32; off > 0; off >>= 1)
        ssum += __shfl_xor(ssum, off, 64);
    if ((tid & 63) == 0) red[4 + wid] = ssum;
    __syncthreads();
    const float total = red[4] + red[5] + red[6] + red[7];
    if (tid < SS) wl[tid] = e / total;
    __syncthreads();

    const int wv = tid >> 6, h = tid & 63;
    float p = 0.0f;
    for (int s = wv * 50; s < wv * 50 + 50; ++s)
        p += k_s[s * (PADQ * 4) + h] * wl[s];
    part[wv * 64 + h] = p;
    __syncthreads();
    if (tid < 64) {
        float r = part[tid] + part[64 + tid] + part[128 + tid] + part[192 + tid];
        out[(size_t)bw * HH + tid] = r;
    }
}

extern "C" void kernel_launch(void* const* d_in, const int* in_sizes, int n_in,
                              void* d_out, int out_size, void* d_ws, size_t ws_size,
                              hipStream_t stream) {
    const float* query   = (const float*)d_in[0];
    const float* key     = (const float*)d_in[1];
    const float* W1      = (const float*)d_in[2];
    const float* b1      = (const float*)d_in[3];
    const float* prelu_a = (const float*)d_in[4];
    const float* W2      = (const float*)d_in[5];
    const float* b2      = (const float*)d_in[6];
    const int*   mask    = (const int*)d_in[7];
    float* out = (float*)d_out;

    const size_t need = (size_t)(BB * FFN * HH + BB * FFN) * sizeof(float);
    if (ws_size >= need) {
        float* c_ws = (float*)d_ws;
        float* A_ws = c_ws + BB * FFN * HH;
        precompute_c<<<BB, 256, 0, stream>>>(query, W1, b1, c_ws, A_ws);
        twb_main<<<BB * WW, 256, 0, stream>>>(key, c_ws, A_ws, prelu_a,
                                              W2, b2, mask, out);
    } else {
        twb_fallback<<<BB * WW, 256, 0, stream>>>(query, key, W1, b1, prelu_a,
                                                  W2, b2, mask, out);
    }
}

// Round 5
// 378.298 us; speedup vs baseline: 1.7537x; 1.3267x over previous
//
#include <hip/hip_runtime.h>
#include <math.h>

// TimeWindowBlock round 5.
// R1-R4 post-mortems: every VALU formulation of the score GEMM stalls on
// operand delivery (broadcast LDS / per-lane VMEM / serialized SMEM);
// MfmaUtil was 0.0 throughout. R5 moves the (200x64)@(64x36) score GEMM per
// block onto mfma_f32_16x16x32_bf16. k split hi+lo bf16 (2 MFMA passes ->
// ~2^-18 k error), c single bf16. B-frags (c) loaded once per wave.
// Phase-2 weighted sum reconstructs k = hi+lo. Expect HBM-streaming-bound.

#define BB   512
#define WW   8
#define SS   200
#define HH   64
#define FFN  36
#define SCST 72            // c LDS row stride in bf16 (144 B, 16B-aligned)

typedef __attribute__((ext_vector_type(8))) short short8;
typedef __attribute__((ext_vector_type(4))) float f32x4;

__device__ __forceinline__ unsigned short f2bf(float x) {
    union { float f; unsigned u; } v; v.f = x;
    unsigned r = v.u + 0x7fffu + ((v.u >> 16) & 1u);   // RNE
    return (unsigned short)(r >> 16);
}
__device__ __forceinline__ float bf2f(unsigned short h) {
    union { unsigned u; float f; } v; v.u = ((unsigned)h) << 16;
    return v.f;
}

// ---------------- kernel A: c_hi[b][48][64] bf16, A[b][48] f32 ----------------
__global__ __launch_bounds__(256)
void precompute_c(const float* __restrict__ query,
                  const float* __restrict__ W1,
                  const float* __restrict__ b1,
                  unsigned short* __restrict__ c_hi_g,
                  float* __restrict__ A_g)
{
    __shared__ float q_s[HH];
    const int b = blockIdx.x, tid = threadIdx.x;
    if (tid < HH) q_s[tid] = query[b * HH + tid];
    __syncthreads();
    for (int idx = tid; idx < 48 * HH; idx += 256) {
        int o = idx >> 6, h = idx & 63;
        float c = 0.0f;
        if (o < FFN) {
            const float* w = W1 + o * 4 * HH;
            c = w[HH + h] - w[2 * HH + h] + w[3 * HH + h] * q_s[h];
        }
        c_hi_g[(size_t)b * 48 * HH + idx] = f2bf(c);
    }
    if (tid < 48) {
        float a = 0.0f;
        if (tid < FFN) {
            const float* w = W1 + tid * 4 * HH;
            a = b1[tid];
            #pragma unroll 8
            for (int h = 0; h < HH; ++h) a += (w[h] + w[2 * HH + h]) * q_s[h];
        }
        A_g[b * 48 + tid] = a;
    }
}

// ---------------- kernel B: main ----------------
__global__ __launch_bounds__(256, 2)
void twb_main(const float* __restrict__ key,
              const unsigned short* __restrict__ c_hi_g,
              const float* __restrict__ A_g,
              const float* __restrict__ prelu_a,
              const float* __restrict__ W2,
              const int*   __restrict__ mask,
              float*       __restrict__ out)
{
    // 208 rows: 13 s-tiles of 16; rows 200..207 zeroed.
    // XOR-swizzled 8-elem chunks: elem(s,h) = s*64 + (((h>>3)^s)&7)*8 + (h&7)
    __shared__ unsigned short k_hi[208 * HH];   // 26,624 B
    __shared__ unsigned short k_lo[208 * HH];   // 26,624 B
    __shared__ unsigned short c_s[48 * SCST];   //  6,912 B
    __shared__ float A_s[48], W2_s[48];
    __shared__ float scores[208];
    __shared__ float wl[208];
    __shared__ float red[8];
    __shared__ float part[256];

    const int tid = threadIdx.x;
    const int bw  = blockIdx.x;
    const int b   = bw >> 3;

    // ---- stage key: global float4 -> bf16 hi/lo -> swizzled LDS ----
    const float4* gk4 = (const float4*)(key + (size_t)bw * (SS * HH));
    for (int i = tid; i < (SS * HH) / 4; i += 256) {
        float4 v = gk4[i];
        int s = i >> 4, h = (i & 15) * 4;
        ushort4 hi, lo;
        hi.x = f2bf(v.x); lo.x = f2bf(v.x - bf2f(hi.x));
        hi.y = f2bf(v.y); lo.y = f2bf(v.y - bf2f(hi.y));
        hi.z = f2bf(v.z); lo.z = f2bf(v.z - bf2f(hi.z));
        hi.w = f2bf(v.w); lo.w = f2bf(v.w - bf2f(hi.w));
        int off = s * HH + ((((h >> 3) ^ s) & 7) << 3) + (h & 7);
        *(ushort4*)(k_hi + off) = hi;
        *(ushort4*)(k_lo + off) = lo;
    }
    for (int i = tid; i < 8 * HH; i += 256) {    // zero tail rows 200..207
        k_hi[SS * HH + i] = 0; k_lo[SS * HH + i] = 0;
    }
    // ---- stage c (bf16) ----
    const unsigned* cg = (const unsigned*)(c_hi_g + (size_t)b * 48 * HH);
    for (int i = tid; i < 48 * HH / 2; i += 256) {
        int o = i >> 5, p = i & 31;
        *(unsigned*)(c_s + o * SCST + 2 * p) = cg[i];
    }
    if (tid < 48) {
        A_s[tid]  = A_g[b * 48 + tid];
        W2_s[tid] = (tid < FFN) ? W2[tid] : 0.0f;
    }
    __syncthreads();

    // ---- phase 1: MFMA score GEMM ----
    const int lane = tid & 63, q = lane >> 4, n = lane & 15, wid = tid >> 6;
    short8 Bf[3][2];
    #pragma unroll
    for (int ot = 0; ot < 3; ++ot)
        #pragma unroll
        for (int ks = 0; ks < 2; ++ks)
            Bf[ot][ks] = *(const short8*)(c_s + (ot * 16 + n) * SCST + ks * 32 + q * 8);

    const float pa = prelu_a[0];
    for (int st = wid; st < 13; st += 4) {
        const int s = st * 16 + n;
        short8 Ah[2], Al[2];
        #pragma unroll
        for (int ks = 0; ks < 2; ++ks) {
            int off = s * HH + ((((ks * 4 + q) ^ s) & 7) << 3);
            Ah[ks] = *(const short8*)(k_hi + off);
            Al[ks] = *(const short8*)(k_lo + off);
        }
        float contrib[4] = {0.f, 0.f, 0.f, 0.f};
        #pragma unroll
        for (int ot = 0; ot < 3; ++ot) {
            f32x4 acc = {0.f, 0.f, 0.f, 0.f};
            acc = __builtin_amdgcn_mfma_f32_16x16x32_bf16(Ah[0], Bf[ot][0], acc, 0, 0, 0);
            acc = __builtin_amdgcn_mfma_f32_16x16x32_bf16(Al[0], Bf[ot][0], acc, 0, 0, 0);
            acc = __builtin_amdgcn_mfma_f32_16x16x32_bf16(Ah[1], Bf[ot][1], acc, 0, 0, 0);
            acc = __builtin_amdgcn_mfma_f32_16x16x32_bf16(Al[1], Bf[ot][1], acc, 0, 0, 0);
            const int o = ot * 16 + n;
            const float Ao = A_s[o], w2o = W2_s[o];
            #pragma unroll
            for (int r = 0; r < 4; ++r) {
                float hv = acc[r] + Ao;
                hv = (hv >= 0.0f) ? hv : pa * hv;
                contrib[r] += w2o * hv;
            }
        }
        #pragma unroll
        for (int m = 1; m <= 8; m <<= 1)
            #pragma unroll
            for (int r = 0; r < 4; ++r)
                contrib[r] += __shfl_xor(contrib[r], m, 64);
        if (n == 0) {
            #pragma unroll
            for (int r = 0; r < 4; ++r) {
                int ss = st * 16 + q * 4 + r;
                if (ss < SS) scores[ss] = contrib[r];
            }
        }
    }
    __syncthreads();

    // ---- mask + softmax over S ----
    float msc = -3.0e38f;
    if (tid < SS)
        msc = mask[bw * SS + tid] ? -10000.0f : scores[tid];
    float mx = msc;
    #pragma unroll
    for (int off = 32; off > 0; off >>= 1)
        mx = fmaxf(mx, __shfl_xor(mx, off, 64));
    if (lane == 0) red[wid] = mx;
    __syncthreads();
    const float M = fmaxf(fmaxf(red[0], red[1]), fmaxf(red[2], red[3]));
    float e = (tid < SS) ? __expf(msc - M) : 0.0f;
    float ssum = e;
    #pragma unroll
    for (int off = 32; off > 0; off >>= 1)
        ssum += __shfl_xor(ssum, off, 64);
    if (lane == 0) red[4 + wid] = ssum;
    __syncthreads();
    const float total = red[4] + red[5] + red[6] + red[7];
    if (tid < SS) wl[tid] = e / total;
    __syncthreads();

    // ---- phase 2: out[h] = sum_s (k_hi+k_lo)[s][h] * wl[s] ----
    float p2 = 0.0f;
    for (int s2 = wid * 50; s2 < wid * 50 + 50; ++s2) {
        int off = s2 * HH + ((((lane >> 3) ^ s2) & 7) << 3) + (lane & 7);
        float kv = bf2f(k_hi[off]) + bf2f(k_lo[off]);
        p2 += kv * wl[s2];
    }
    part[wid * 64 + lane] = p2;
    __syncthreads();
    if (tid < 64) {
        float r = part[tid] + part[64 + tid] + part[128 + tid] + part[192 + tid];
        out[(size_t)bw * HH + tid] = r;
    }
}

// ---------------- fallback (round-1 kernel, used if ws too small) ----------------
#define PADQ 17
__global__ __launch_bounds__(256, 2)
void twb_fallback(const float* __restrict__ query,
                  const float* __restrict__ key,
                  const float* __restrict__ W1,
                  const float* __restrict__ b1,
                  const float* __restrict__ prelu_a,
                  const float* __restrict__ W2,
                  const float* __restrict__ b2,
                  const int*   __restrict__ mask,
                  float*       __restrict__ out)
{
    __shared__ float q_s[HH];
    __shared__ float c_s[FFN * HH];
    __shared__ float A_s[FFN];
    __shared__ float W2_s[FFN];
    __shared__ float k_s[SS * PADQ * 4];
    __shared__ float wl[256];
    __shared__ float red[8];
    __shared__ float part[4 * 64];

    const int tid = threadIdx.x;
    const int bw  = blockIdx.x;
    const int b   = bw >> 3;

    if (tid < HH)  q_s[tid]  = query[b * HH + tid];
    if (tid < FFN) W2_s[tid] = W2[tid];
    __syncthreads();

    const float4* gk4 = (const float4*)(key + (size_t)bw * (SS * HH));
    float4* kl4 = (float4*)k_s;
    for (int i = tid; i < (SS * HH) / 4; i += 256) {
        float4 v = gk4[i];
        kl4[(i >> 4) * PADQ + (i & 15)] = v;
    }
    for (int idx = tid; idx < FFN * HH; idx += 256) {
        int o = idx >> 6, h = idx & 63;
        const float* w = W1 + o * (4 * HH);
        c_s[idx] = w[HH + h] - w[2 * HH + h] + w[3 * HH + h] * q_s[h];
    }
    if (tid < FFN) {
        const float* w = W1 + tid * (4 * HH);
        float a = b1[tid];
        for (int h = 0; h < HH; ++h) a += (w[h] + w[2 * HH + h]) * q_s[h];
        A_s[tid] = a;
    }
    __syncthreads();

    const float pa  = prelu_a[0];
    const float bb2 = b2[0];
    float msc = -3.0e38f;
    if (tid < SS) {
        float acc[FFN];
        #pragma unroll
        for (int o = 0; o < FFN; ++o) acc[o] = A_s[o];
        const float4* c4 = (const float4*)c_s;
        const float4* k4 = (const float4*)k_s;
        const int rowbase = tid * PADQ;
        for (int ch = 0; ch < 4; ++ch) {
            float4 kv0 = k4[rowbase + ch * 4 + 0];
            float4 kv1 = k4[rowbase + ch * 4 + 1];
            float4 kv2 = k4[rowbase + ch * 4 + 2];
            float4 kv3 = k4[rowbase + ch * 4 + 3];
            #pragma unroll
            for (int o = 0; o < FFN; ++o) {
                float4 c0 = c4[o * 16 + ch * 4 + 0];
                float4 c1 = c4[o * 16 + ch * 4 + 1];
                float4 c2 = c4[o * 16 + ch * 4 + 2];
                float4 c3 = c4[o * 16 + ch * 4 + 3];
                float a = acc[o];
                a += c0.x * kv0.x + c0.y * kv0.y + c0.z * kv0.z + c0.w * kv0.w;
                a += c1.x * kv1.x + c1.y * kv1.y + c1.z * kv1.z + c1.w * kv1.w;
                a += c2.x * kv2.x + c2.y * kv2.y + c2.z * kv2.z + c2.w * kv2.w;
                a += c3.x * kv3.x + c3.y * kv3.y + c3.z * kv3.z + c3.w * kv3.w;
                acc[o] = a;
            }
        }
        float sc = bb2;
        #pragma unroll
        for (int o = 0; o < FFN; ++o) {
            float a = acc[o];
            a = (a >= 0.0f) ? a : pa * a;
            sc += W2_s[o] * a;
        }
        msc = mask[bw * SS + tid] ? -10000.0f : sc;
    }

    float mx = msc;
    #pragma unroll
    for (int off = 32; off > 0; off >>= 1)
        mx = fmaxf(mx, __shfl_xor(mx, off, 64));
    const int wid = tid >> 6;
    if ((tid & 63) == 0) red[wid] = mx;
    __syncthreads();
    const float M = fmaxf(fmaxf(red[0], red[1]), fmaxf(red[2], red[3]));
    float e = (tid < SS) ? __expf(msc - M) : 0.0f;
    float ssum = e;
    #pragma unroll
    for (int off = 32; off > 0; off >>= 1)
        ssum += __shfl_xor(ssum, off, 64);
    if ((tid & 63) == 0) red[4 + wid] = ssum;
    __syncthreads();
    const float total = red[4] + red[5] + red[6] + red[7];
    if (tid < SS) wl[tid] = e / total;
    __syncthreads();

    const int wv = tid >> 6, h = tid & 63;
    float p = 0.0f;
    for (int s = wv * 50; s < wv * 50 + 50; ++s)
        p += k_s[s * (PADQ * 4) + h] * wl[s];
    part[wv * 64 + h] = p;
    __syncthreads();
    if (tid < 64) {
        float r = part[tid] + part[64 + tid] + part[128 + tid] + part[192 + tid];
        out[(size_t)bw * HH + tid] = r;
    }
}

extern "C" void kernel_launch(void* const* d_in, const int* in_sizes, int n_in,
                              void* d_out, int out_size, void* d_ws, size_t ws_size,
                              hipStream_t stream) {
    const float* query   = (const float*)d_in[0];
    const float* key     = (const float*)d_in[1];
    const float* W1      = (const float*)d_in[2];
    const float* b1      = (const float*)d_in[3];
    const float* prelu_a = (const float*)d_in[4];
    const float* W2      = (const float*)d_in[5];
    const float* b2      = (const float*)d_in[6];
    const int*   mask    = (const int*)d_in[7];
    float* out = (float*)d_out;

    const size_t c_bytes = (size_t)BB * 48 * HH * sizeof(unsigned short); // 3.15 MB
    const size_t a_bytes = (size_t)BB * 48 * sizeof(float);               // 98 KB
    if (ws_size >= c_bytes + a_bytes) {
        unsigned short* c_hi_g = (unsigned short*)d_ws;
        float* A_g = (float*)((char*)d_ws + c_bytes);
        precompute_c<<<BB, 256, 0, stream>>>(query, W1, b1, c_hi_g, A_g);
        twb_main<<<BB * WW, 256, 0, stream>>>(key, c_hi_g, A_g, prelu_a,
                                              W2, mask, out);
    } else {
        twb_fallback<<<BB * WW, 256, 0, stream>>>(query, key, W1, b1, prelu_a,
                                                  W2, b2, mask, out);
    }
}